// Round 2
// baseline (13072.588 us; speedup 1.0000x reference)
//
#include <hip/hip_runtime.h>
#include <hip/hip_bf16.h>
#include <math.h>

#define TS 32

// ---------- type helpers ----------
__device__ __forceinline__ float ldf(const float* p) { return *p; }
__device__ __forceinline__ float ldf(const __hip_bfloat16* p) { return __bfloat162float(*p); }
__device__ __forceinline__ void stf(float* p, float v) { *p = v; }
__device__ __forceinline__ void stf(__hip_bfloat16* p, float v) { *p = __float2bfloat16(v); }

// ---------- dense GEMM: C[M,N] = act(A[M,K] @ B[K,N] + bias[N]) (+ optional gated skip) ----
// K and N are multiples of 32 here (64/128/192/256/384).
template <typename TA, typename TC>
__global__ void gemm_bias(const TA* __restrict__ A, const float* __restrict__ B,
                          const float* __restrict__ bias, TC* __restrict__ C,
                          int M, int N, int K, int act,
                          const TC* __restrict__ res, const float* __restrict__ skip_arr, int t) {
    __shared__ float As[TS][TS + 1];
    __shared__ float Bs[TS][TS + 1];
    int tx = threadIdx.x, ty = threadIdx.y;
    int row = blockIdx.y * TS + ty;
    int col = blockIdx.x * TS + tx;
    float acc = 0.f;
    for (int k0 = 0; k0 < K; k0 += TS) {
        As[ty][tx] = (row < M) ? ldf(A + (long)row * K + k0 + tx) : 0.f;
        Bs[ty][tx] = (col < N) ? B[(long)(k0 + ty) * N + col] : 0.f;
        __syncthreads();
        #pragma unroll
        for (int kk = 0; kk < TS; ++kk) acc = fmaf(As[ty][kk], Bs[kk][tx], acc);
        __syncthreads();
    }
    if (row < M && col < N) {
        acc += bias[col];
        if (act == 1) acc = fmaxf(acc, 0.f);
        if (res != nullptr) {
            float s = skip_arr[t];
            float a = 1.f / (1.f + expf(-s));
            acc = a * acc + (1.f - a) * ldf(res + (long)row * N + col);
        }
        stf(C + (long)row * N + col, acc);
    }
}

__global__ void fill_u32(unsigned int* __restrict__ p, unsigned int v, long n) {
    long i = blockIdx.x * (long)blockDim.x + threadIdx.x;
    if (i < n) p[i] = v;
}

// ---------- edge pass 1: score + segment-max (order-preserving uint atomicMax) ----------
template <typename TK>
__global__ void edge_score(const TK* __restrict__ Ksrc, const TK* __restrict__ Qdst,
                           int stride, int H,
                           const int* __restrict__ src, const int* __restrict__ dst, int E,
                           const float* __restrict__ krel, const float* __restrict__ prel,
                           float scale, float* __restrict__ sc_out,
                           unsigned int* __restrict__ m_enc) {
    __shared__ float sM[2048];
    __shared__ float sP[8];
    int nload = H * 256;
    for (int i = threadIdx.x; i < nload; i += blockDim.x) sM[i] = krel[i];
    if ((int)threadIdx.x < H) sP[threadIdx.x] = prel[threadIdx.x];
    __syncthreads();
    long tid = blockIdx.x * (long)blockDim.x + threadIdx.x;
    if (tid >= (long)E * H) return;
    int e = (int)(tid / H);
    int h = (int)(tid - (long)e * H);
    int s = src[e], d = dst[e];
    const TK* kp = Ksrc + (long)s * stride + h * 16;
    const TK* qp = Qdst + (long)d * stride + h * 16;
    const float* km = sM + h * 256;
    float kv[16];
    #pragma unroll
    for (int i = 0; i < 16; i++) kv[i] = ldf(kp + i);
    float acc = 0.f;
    #pragma unroll
    for (int j = 0; j < 16; j++) {
        float kr = 0.f;
        #pragma unroll
        for (int i = 0; i < 16; i++) kr = fmaf(kv[i], km[i * 16 + j], kr);
        acc = fmaf(kr, ldf(qp + j), acc);
    }
    float v = acc * sP[h] * scale;
    sc_out[tid] = v;
    unsigned int u = __float_as_uint(v);
    u = (u & 0x80000000u) ? ~u : (u | 0x80000000u);
    atomicMax(m_enc + (long)d * H + h, u);
}

// ---------- edge pass 2: exp(sc - max) + denominator ----------
__global__ void edge_exp(float* __restrict__ sc, const int* __restrict__ dst, int E, int H,
                         const unsigned int* __restrict__ m_enc, float* __restrict__ den) {
    long tid = blockIdx.x * (long)blockDim.x + threadIdx.x;
    if (tid >= (long)E * H) return;
    int e = (int)(tid / H);
    int h = (int)(tid - (long)e * H);
    int d = dst[e];
    unsigned int u = m_enc[(long)d * H + h];
    float m = (u & 0x80000000u) ? __uint_as_float(u & 0x7FFFFFFFu) : __uint_as_float(~u);
    float ex = expf(sc[tid] - m);
    sc[tid] = ex;
    atomicAdd(den + (long)d * H + h, ex);
}

// ---------- edge pass 3: agg[dst] += alpha * (v[src,h,:] @ vrel[h]) ----------
template <typename TK>
__global__ void edge_agg(const TK* __restrict__ Vsrc, int stride, int H, int fout,
                         const int* __restrict__ src, const int* __restrict__ dst, int E,
                         const float* __restrict__ vrel,
                         const float* __restrict__ ex, const float* __restrict__ den,
                         float* __restrict__ agg) {
    __shared__ float sM[2048];
    int nload = H * 256;
    for (int i = threadIdx.x; i < nload; i += blockDim.x) sM[i] = vrel[i];
    __syncthreads();
    long tid = blockIdx.x * (long)blockDim.x + threadIdx.x;
    if (tid >= (long)E * H) return;
    int e = (int)(tid / H);
    int h = (int)(tid - (long)e * H);
    int s = src[e], d = dst[e];
    float alpha = ex[tid] / fmaxf(den[(long)d * H + h], 1e-16f);
    const TK* vp = Vsrc + (long)s * stride + h * 16;
    const float* vm = sM + h * 256;
    float vv[16];
    #pragma unroll
    for (int i = 0; i < 16; i++) vv[i] = ldf(vp + i);
    float* ap = agg + (long)d * fout + h * 16;
    #pragma unroll
    for (int j = 0; j < 16; j++) {
        float vr = 0.f;
        #pragma unroll
        for (int i = 0; i < 16; i++) vr = fmaf(vv[i], vm[i * 16 + j], vr);
        atomicAdd(ap + j, vr * alpha);
    }
}

__global__ void gelu_ip(float* __restrict__ x, long n) {
    long i = blockIdx.x * (long)blockDim.x + threadIdx.x;
    if (i >= n) return;
    float v = x[i];
    x[i] = 0.5f * v * (1.f + erff(v * 0.70710678118654752f));
}

// ---------- orchestration ----------
static const int ET_src[5] = {1, 0, 0, 1, 2};
static const int ET_dst[5] = {0, 0, 1, 2, 1};
static const int ET_E[5]   = {250000, 250000, 200000, 100000, 100000};
static const int NT[3]     = {100000, 50000, 5000};
static const long NPRE[3]  = {0, 100000, 150000};

template <typename TXS, typename TK, typename TO>
static void hgt_layer_run(hipStream_t stream, const int* const* ei,
                          const TXS* xs, TK* kqvB, float* scB, unsigned int* mB,
                          float* denB, float* aggB,
                          const float* kqv_w, const float* kqv_b, const float* krel,
                          const float* vrel, const float* prel, const float* out_w,
                          const float* out_b, const float* skip_arr,
                          int H, int fout, bool do_skip, TO* const* outs) {
    const int F3 = 3 * fout;
    dim3 gblk(32, 32);
    for (int t = 0; t < 3; t++) {
        dim3 grid(F3 / TS, (NT[t] + TS - 1) / TS);
        gemm_bias<TXS, TK><<<grid, gblk, 0, stream>>>(
            xs + NPRE[t] * 128, kqv_w + (long)t * 128 * F3, kqv_b + t * F3,
            kqvB + NPRE[t] * F3, NT[t], F3, 128, 0, (TK*)nullptr, nullptr, 0);
    }
    for (int t = 0; t < 3; t++) {
        long nh = (long)NT[t] * H;
        long na = (long)NT[t] * fout;
        fill_u32<<<(int)((nh + 255) / 256), 256, 0, stream>>>(mB, 0x007FFFFFu, nh); // enc(-inf)
        fill_u32<<<(int)((nh + 255) / 256), 256, 0, stream>>>((unsigned int*)denB, 0u, nh);
        fill_u32<<<(int)((na + 255) / 256), 256, 0, stream>>>((unsigned int*)aggB, 0u, na);
        long scoff = 0;
        for (int e = 0; e < 5; e++) {
            if (ET_dst[e] != t) continue;
            int E = ET_E[e], s = ET_src[e];
            long tot = (long)E * H;
            edge_score<TK><<<(int)((tot + 255) / 256), 256, 0, stream>>>(
                kqvB + NPRE[s] * F3, kqvB + NPRE[t] * F3 + fout, F3, H,
                ei[e], ei[e] + E, E, krel + (long)e * H * 256, prel + e * H, 0.25f,
                scB + scoff, mB);
            scoff += tot;
        }
        scoff = 0;
        for (int e = 0; e < 5; e++) {
            if (ET_dst[e] != t) continue;
            int E = ET_E[e];
            long tot = (long)E * H;
            edge_exp<<<(int)((tot + 255) / 256), 256, 0, stream>>>(scB + scoff, ei[e] + E, E, H,
                                                                   mB, denB);
            scoff += tot;
        }
        scoff = 0;
        for (int e = 0; e < 5; e++) {
            if (ET_dst[e] != t) continue;
            int E = ET_E[e], s = ET_src[e];
            long tot = (long)E * H;
            edge_agg<TK><<<(int)((tot + 255) / 256), 256, 0, stream>>>(
                kqvB + NPRE[s] * F3 + 2 * fout, F3, H, fout, ei[e], ei[e] + E, E,
                vrel + (long)e * H * 256, scB + scoff, denB, aggB);
            scoff += tot;
        }
        gelu_ip<<<(int)((na + 255) / 256), 256, 0, stream>>>(aggB, na);
        dim3 grid2(fout / TS, (NT[t] + TS - 1) / TS);
        gemm_bias<float, TO><<<grid2, gblk, 0, stream>>>(
            aggB, out_w + (long)t * fout * fout, out_b + t * fout, outs[t],
            NT[t], fout, fout, 0,
            do_skip ? outs[t] : (TO*)nullptr, skip_arr, t);
    }
}

template <typename TXS, typename TK>
static void run_model(void* const* d_in, void* d_out, void* d_ws, hipStream_t stream) {
    const float* x_paper  = (const float*)d_in[0];
    const float* x_author = (const float*)d_in[1];
    const float* x_inst   = (const float*)d_in[2];
    const int* ei[5];
    for (int e = 0; e < 5; e++) ei[e] = (const int*)d_in[3 + e];
    const float* lin_w[3] = {(const float*)d_in[8], (const float*)d_in[10], (const float*)d_in[12]};
    const float* lin_b[3] = {(const float*)d_in[9], (const float*)d_in[11], (const float*)d_in[13]};
    const float* kqv_w1 = (const float*)d_in[14];
    const float* kqv_b1 = (const float*)d_in[15];
    const float* krel1  = (const float*)d_in[16];
    const float* vrel1  = (const float*)d_in[17];
    const float* prel1  = (const float*)d_in[18];
    const float* out_w1 = (const float*)d_in[19];
    const float* out_b1 = (const float*)d_in[20];
    const float* skip1  = (const float*)d_in[21];
    const float* kqv_w2 = (const float*)d_in[22];
    const float* kqv_b2 = (const float*)d_in[23];
    const float* krel2  = (const float*)d_in[24];
    const float* vrel2  = (const float*)d_in[25];
    const float* prel2  = (const float*)d_in[26];
    const float* out_w2 = (const float*)d_in[27];
    const float* out_b2 = (const float*)d_in[28];
    const float* skip2  = (const float*)d_in[29];

    // workspace carve (element counts)
    const long XS_N = 19840000L, KQV_N = 59520000L, SC_N = 4000000L;
    const long M_N = 800000L, AGG_N = 12800000L;
    char* p = (char*)d_ws;
    TXS* xs = (TXS*)p;            p += XS_N * sizeof(TXS);
    TK* kqvB = (TK*)p;            p += KQV_N * sizeof(TK);
    float* scB = (float*)p;       p += SC_N * 4;
    unsigned int* mB = (unsigned int*)p; p += M_N * 4;
    float* denB = (float*)p;      p += M_N * 4;
    float* aggB = (float*)p;

    dim3 gblk(32, 32);
    gemm_bias<float, TXS><<<dim3(128 / TS, 3125), gblk, 0, stream>>>(
        x_paper, lin_w[0], lin_b[0], xs, 100000, 128, 256, 1, (TXS*)nullptr, nullptr, 0);
    gemm_bias<float, TXS><<<dim3(128 / TS, 1563), gblk, 0, stream>>>(
        x_author, lin_w[1], lin_b[1], xs + 100000L * 128, 50000, 128, 128, 1, (TXS*)nullptr, nullptr, 0);
    gemm_bias<float, TXS><<<dim3(128 / TS, 157), gblk, 0, stream>>>(
        x_inst, lin_w[2], lin_b[2], xs + 150000L * 128, 5000, 128, 64, 1, (TXS*)nullptr, nullptr, 0);

    // layer 1: output written IN-PLACE over xs (skip fused into out-GEMM epilogue)
    TXS* outs1[3] = {xs, xs + 100000L * 128, xs + 150000L * 128};
    hgt_layer_run<TXS, TK, TXS>(stream, ei, xs, kqvB, scB, mB, denB, aggB,
                                kqv_w1, kqv_b1, krel1, vrel1, prel1, out_w1, out_b1, skip1,
                                8, 128, true, outs1);

    float* out = (float*)d_out;
    float* outs2[3] = {out, out + 100000L * 64, out + 150000L * 64};
    hgt_layer_run<TXS, TK, float>(stream, ei, xs, kqvB, scB, mB, denB, aggB,
                                  kqv_w2, kqv_b2, krel2, vrel2, prel2, out_w2, out_b2, skip2,
                                  4, 64, false, outs2);
}

extern "C" void kernel_launch(void* const* d_in, const int* in_sizes, int n_in,
                              void* d_out, int out_size, void* d_ws, size_t ws_size,
                              hipStream_t stream) {
    // adaptive workspace: pick the highest-precision layout that fits (ws_size is
    // constant across calls, so this branch is graph-stable)
    const size_t bytesA = 19840000UL * 4 + 59520000UL * 4 + (4000000UL + 800000UL + 800000UL + 12800000UL) * 4; // 391.0 MB
    const size_t bytesB = 19840000UL * 4 + 59520000UL * 2 + (4000000UL + 800000UL + 800000UL + 12800000UL) * 4; // 272.0 MB
    if (ws_size >= bytesA) {
        run_model<float, float>(d_in, d_out, d_ws, stream);
    } else if (ws_size >= bytesB) {
        run_model<float, __hip_bfloat16>(d_in, d_out, d_ws, stream);
    } else {
        run_model<__hip_bfloat16, __hip_bfloat16>(d_in, d_out, d_ws, stream);
    }
}

// Round 3
// 3230.190 us; speedup vs baseline: 4.0470x; 4.0470x over previous
//
#include <hip/hip_runtime.h>
#include <hip/hip_bf16.h>
#include <math.h>

// ---------- type helpers ----------
__device__ __forceinline__ float ldf(const float* p) { return *p; }
__device__ __forceinline__ float ldf(const __hip_bfloat16* p) { return __bfloat162float(*p); }
__device__ __forceinline__ void stf(float* p, float v) { *p = v; }
__device__ __forceinline__ void stf(__hip_bfloat16* p, float v) { *p = __float2bfloat16(v); }
__device__ __forceinline__ float gelu1(float v) {
    return 0.5f * v * (1.f + erff(v * 0.70710678118654752f));
}

// ---------- 64x64 register-tiled GEMM: C = act(A@B + bias) (+ gated skip) ----------
// N % 64 == 0, K % 16 == 0 always in this model. A: [M,K] row-major, B: [K,N] row-major.
template <typename TA, typename TC>
__global__ void gemm64(const TA* __restrict__ A, const float* __restrict__ B,
                       const float* __restrict__ bias, TC* __restrict__ C,
                       int M, int N, int K, int act,
                       const TC* __restrict__ res, const float* __restrict__ skip_arr, int t) {
    __shared__ float As[16][65];
    __shared__ float Bs[16][65];
    int tid = threadIdx.x;
    int tx = tid & 15, ty = tid >> 4;
    int row0 = blockIdx.y * 64, col0 = blockIdx.x * 64;
    float acc[4][4] = {};
    int ar = tid >> 2;        // 0..63  (A row within tile)
    int ak = (tid & 3) * 4;   // 0,4,8,12 (A k within tile)
    int bk = tid >> 4;        // 0..15  (B k within tile)
    int bc = (tid & 15) * 4;  // 0..60  (B col within tile)
    for (int k0 = 0; k0 < K; k0 += 16) {
        int grow = row0 + ar;
        #pragma unroll
        for (int q = 0; q < 4; q++)
            As[ak + q][ar] = (grow < M) ? ldf(A + (long)grow * K + k0 + ak + q) : 0.f;
        #pragma unroll
        for (int q = 0; q < 4; q++)
            Bs[bk][bc + q] = B[(long)(k0 + bk) * N + col0 + bc + q];
        __syncthreads();
        #pragma unroll
        for (int kk = 0; kk < 16; kk++) {
            float a[4], b[4];
            #pragma unroll
            for (int i = 0; i < 4; i++) a[i] = As[kk][ty * 4 + i];
            #pragma unroll
            for (int j = 0; j < 4; j++) b[j] = Bs[kk][tx * 4 + j];
            #pragma unroll
            for (int i = 0; i < 4; i++)
                #pragma unroll
                for (int j = 0; j < 4; j++)
                    acc[i][j] = fmaf(a[i], b[j], acc[i][j]);
        }
        __syncthreads();
    }
    float aval = 0.f;
    if (res != nullptr) { float s = skip_arr[t]; aval = 1.f / (1.f + __expf(-s)); }
    #pragma unroll
    for (int i = 0; i < 4; i++) {
        int row = row0 + ty * 4 + i;
        if (row >= M) continue;
        #pragma unroll
        for (int j = 0; j < 4; j++) {
            int col = col0 + tx * 4 + j;
            float v = acc[i][j] + bias[col];
            if (act == 1) v = fmaxf(v, 0.f);
            if (res != nullptr) v = aval * v + (1.f - aval) * ldf(res + (long)row * N + col);
            stf(C + (long)row * N + col, v);
        }
    }
}

// ---------- small utils ----------
__global__ void fill_u32(unsigned int* __restrict__ p, unsigned int v, int n) {
    int i = blockIdx.x * blockDim.x + threadIdx.x;
    if (i < n) p[i] = v;
}
__global__ void copy_u32(const int* __restrict__ a, int* __restrict__ b, int n) {
    int i = blockIdx.x * blockDim.x + threadIdx.x;
    if (i < n) b[i] = a[i];
}

// ---------- CSR build ----------
__global__ void count_edges(const int* __restrict__ dst, int E, int* __restrict__ counts) {
    int i = blockIdx.x * blockDim.x + threadIdx.x;
    if (i < E) atomicAdd(&counts[dst[i]], 1);
}
// single-block exclusive scan over n entries (n ~ 155k), 1024 threads, 8 elems/thread
__global__ void scan_excl(const int* __restrict__ counts, int* __restrict__ rowptr, int n) {
    __shared__ int sh[1024];
    int carry = 0;
    const int TILE = 8192;
    for (int base = 0; base < n; base += TILE) {
        int lv[8]; int s = 0;
        #pragma unroll
        for (int q = 0; q < 8; q++) {
            int i = base + threadIdx.x * 8 + q;
            lv[q] = (i < n) ? counts[i] : 0;
            s += lv[q];
        }
        sh[threadIdx.x] = s;
        __syncthreads();
        for (int off = 1; off < 1024; off <<= 1) {
            int add = (threadIdx.x >= (unsigned)off) ? sh[threadIdx.x - off] : 0;
            __syncthreads();
            sh[threadIdx.x] += add;
            __syncthreads();
        }
        int excl = sh[threadIdx.x] - s + carry;
        int tot = sh[1023];
        __syncthreads();
        #pragma unroll
        for (int q = 0; q < 8; q++) {
            int i = base + threadIdx.x * 8 + q;
            if (i < n) rowptr[i] = excl;
            excl += lv[q];
        }
        carry += tot;
    }
    if (threadIdx.x == 0) rowptr[n] = carry;
}
__global__ void scatter_edges(const int* __restrict__ src, const int* __restrict__ dst, int E,
                              int* __restrict__ cursor, int2* __restrict__ recs,
                              int srow_base, int etl) {
    int i = blockIdx.x * blockDim.x + threadIdx.x;
    if (i >= E) return;
    int pos = atomicAdd(&cursor[dst[i]], 1);
    recs[pos] = make_int2(srow_base + src[i], (etl << 28) | i);
}

// ---------- edge pass 1: raw scores (no atomics) ----------
// sc[e,h] = (q[dst,h,:] . (k[src,h,:] @ krel[h])) * prel[h] * scale
template <typename TK>
__global__ void edge_score(const TK* __restrict__ Ksrc, const TK* __restrict__ Qdst,
                           int stride, int H,
                           const int* __restrict__ src, const int* __restrict__ dst, int E,
                           const float* __restrict__ krel, const float* __restrict__ prel,
                           float scale, float* __restrict__ sc_out) {
    __shared__ float sM[2048];
    __shared__ float sP[8];
    int nload = H * 256;
    for (int i = threadIdx.x; i < nload; i += blockDim.x) sM[i] = krel[i];
    if ((int)threadIdx.x < H) sP[threadIdx.x] = prel[threadIdx.x];
    __syncthreads();
    long tid = blockIdx.x * (long)blockDim.x + threadIdx.x;
    if (tid >= (long)E * H) return;
    int e = (int)(tid / H);
    int h = (int)(tid - (long)e * H);
    int s = src[e], d = dst[e];
    const TK* kp = Ksrc + (long)s * stride + h * 16;
    const TK* qp = Qdst + (long)d * stride + h * 16;
    const float* km = sM + h * 256;
    float kv[16];
    #pragma unroll
    for (int i = 0; i < 16; i++) kv[i] = ldf(kp + i);
    float acc = 0.f;
    #pragma unroll
    for (int j = 0; j < 16; j++) {
        float kr = 0.f;
        #pragma unroll
        for (int i = 0; i < 16; i++) kr = fmaf(kv[i], km[i * 16 + j], kr);
        acc = fmaf(kr, ldf(qp + j), acc);
    }
    sc_out[tid] = acc * sP[h] * scale;
}

// ---------- per-destination softmax + gather aggregation (no atomics) ----------
// block = fout threads, one block per dst node. thread j: head h=j/16, lane-in-head jj=j%16.
// phase A: online (m,l) per head via 16-lane shuffle butterfly.
// phase B: acc = sum_e alpha * (v[src] @ vrel)[j]; store gelu(acc).
template <typename TK>
__global__ void gather_agg(const TK* __restrict__ kqv, int F3, int H, int fout,
                           const int2* __restrict__ recs, const int* __restrict__ rowptr, int tb,
                           const float* __restrict__ sc, int sb0, int sb1,
                           const float* __restrict__ vrel0, const float* __restrict__ vrel1,
                           float* __restrict__ agg) {
    __shared__ float sV[4096];  // up to 2 etypes x H x 256
    int nv = H * 256;
    for (int i = threadIdx.x; i < nv; i += blockDim.x) {
        sV[i] = vrel0[i];
        sV[nv + i] = vrel1[i];
    }
    __syncthreads();
    int d = blockIdx.x;
    int r0 = rowptr[tb + d], r1 = rowptr[tb + d + 1];
    int deg = r1 - r0;
    int j = threadIdx.x;
    if (deg == 0) { agg[(long)d * fout + j] = 0.f; return; }
    int h = j >> 4, jj = j & 15;
    // phase A: online softmax stats for head h
    float m = -1e30f, l = 0.f;
    for (int idx = jj; idx < deg; idx += 16) {
        int2 rec = recs[r0 + idx];
        int etl = rec.y >> 28;
        int ei = rec.y & 0x0FFFFFFF;
        float v = sc[(etl ? sb1 : sb0) + ei * H + h];
        float mn = fmaxf(m, v);
        l = l * __expf(m - mn) + __expf(v - mn);
        m = mn;
    }
    #pragma unroll
    for (int off = 1; off < 16; off <<= 1) {
        float mo = __shfl_xor(m, off, 64);
        float lo = __shfl_xor(l, off, 64);
        float mn = fmaxf(m, mo);
        l = l * __expf(m - mn) + lo * __expf(mo - mn);
        m = mn;
    }
    float invden = 1.f / fmaxf(l, 1e-16f);
    // phase B: gather + accumulate
    const TK* vbase = kqv + 2 * fout;
    int gbase = (j & 63) & ~15;  // shuffle source base lane within own wave
    float acc = 0.f;
    for (int idx = 0; idx < deg; ++idx) {
        int2 rec = recs[r0 + idx];
        int srow = rec.x;
        int etl = rec.y >> 28;
        int ei = rec.y & 0x0FFFFFFF;
        float alpha = __expf(sc[(etl ? sb1 : sb0) + ei * H + h] - m) * invden;
        float vv = ldf(vbase + (long)srow * F3 + j);
        const float* vmp = sV + (etl ? nv : 0) + h * 256 + jj;
        float vr = 0.f;
        #pragma unroll
        for (int i = 0; i < 16; i++) {
            float vi = __shfl(vv, gbase + i, 64);
            vr = fmaf(vi, vmp[i * 16], vr);
        }
        acc = fmaf(alpha, vr, acc);
    }
    agg[(long)d * fout + j] = gelu1(acc);
}

// ---------- orchestration ----------
static const int ET_src[5] = {1, 0, 0, 1, 2};
static const int ET_dst[5] = {0, 0, 1, 2, 1};
static const int ET_ETL[5] = {0, 1, 0, 0, 1};  // local etype index within its dst type (ascending e)
static const int ET_E[5]   = {250000, 250000, 200000, 100000, 100000};
static const int NT[3]     = {100000, 50000, 5000};
static const long NPRE[3]  = {0, 100000, 150000};
static const int TB[3]     = {0, 100000, 150000};  // CSR row base per dst type
static const int NTOT      = 155000;

template <typename TXS, typename TK, typename TO>
static void hgt_layer_run(hipStream_t stream, const int* const* ei,
                          const TXS* xs, TK* kqvB, float* scB,
                          const int* rowptr, const int2* recs, float* aggB,
                          const float* kqv_w, const float* kqv_b, const float* krel,
                          const float* vrel, const float* prel, const float* out_w,
                          const float* out_b, const float* skip_arr,
                          int H, int fout, bool do_skip, TO* const* outs) {
    const int F3 = 3 * fout;
    for (int t = 0; t < 3; t++) {
        dim3 grid(F3 / 64, (NT[t] + 63) / 64);
        gemm64<TXS, TK><<<grid, 256, 0, stream>>>(
            xs + NPRE[t] * 128, kqv_w + (long)t * 128 * F3, kqv_b + t * F3,
            kqvB + NPRE[t] * F3, NT[t], F3, 128, 0, (TK*)nullptr, nullptr, 0);
    }
    for (int t = 0; t < 3; t++) {
        long scoff = 0;
        int sb[2] = {0, 0};
        const float* vr[2] = {vrel, vrel};
        int ne = 0;
        for (int e = 0; e < 5; e++) {
            if (ET_dst[e] != t) continue;
            int E = ET_E[e], s = ET_src[e];
            long tot = (long)E * H;
            sb[ne] = (int)scoff;
            vr[ne] = vrel + (long)e * H * 256;
            edge_score<TK><<<(int)((tot + 255) / 256), 256, 0, stream>>>(
                kqvB + NPRE[s] * F3, kqvB + NPRE[t] * F3 + fout, F3, H,
                ei[e], ei[e] + E, E, krel + (long)e * H * 256, prel + e * H, 0.25f,
                scB + scoff);
            scoff += tot;
            ne++;
        }
        if (ne == 1) { sb[1] = sb[0]; vr[1] = vr[0]; }
        gather_agg<TK><<<NT[t], fout, 0, stream>>>(
            kqvB, F3, H, fout, recs, rowptr, TB[t], scB, sb[0], sb[1], vr[0], vr[1], aggB);
        dim3 grid2(fout / 64, (NT[t] + 63) / 64);
        gemm64<float, TO><<<grid2, 256, 0, stream>>>(
            aggB, out_w + (long)t * fout * fout, out_b + t * fout, outs[t],
            NT[t], fout, fout, 0,
            do_skip ? outs[t] : (TO*)nullptr, skip_arr, t);
    }
}

template <typename TXS, typename TK>
static void run_model(void* const* d_in, void* d_out, void* d_ws, hipStream_t stream) {
    const float* x_paper  = (const float*)d_in[0];
    const float* x_author = (const float*)d_in[1];
    const float* x_inst   = (const float*)d_in[2];
    const int* ei[5];
    for (int e = 0; e < 5; e++) ei[e] = (const int*)d_in[3 + e];
    const float* lin_w[3] = {(const float*)d_in[8], (const float*)d_in[10], (const float*)d_in[12]};
    const float* lin_b[3] = {(const float*)d_in[9], (const float*)d_in[11], (const float*)d_in[13]};
    const float* kqv_w1 = (const float*)d_in[14];
    const float* kqv_b1 = (const float*)d_in[15];
    const float* krel1  = (const float*)d_in[16];
    const float* vrel1  = (const float*)d_in[17];
    const float* prel1  = (const float*)d_in[18];
    const float* out_w1 = (const float*)d_in[19];
    const float* out_b1 = (const float*)d_in[20];
    const float* skip1  = (const float*)d_in[21];
    const float* kqv_w2 = (const float*)d_in[22];
    const float* kqv_b2 = (const float*)d_in[23];
    const float* krel2  = (const float*)d_in[24];
    const float* vrel2  = (const float*)d_in[25];
    const float* prel2  = (const float*)d_in[26];
    const float* out_w2 = (const float*)d_in[27];
    const float* out_b2 = (const float*)d_in[28];
    const float* skip2  = (const float*)d_in[29];

    // workspace carve
    const long XS_N = 19840000L, KQV_N = 59520000L, SC_N = 4000000L, AGG_N = 12800000L;
    char* p = (char*)d_ws;
    TXS* xs = (TXS*)p;                   p += XS_N * sizeof(TXS);
    TK* kqvB = (TK*)p;                   p += KQV_N * sizeof(TK);
    float* scB = (float*)p;              p += SC_N * 4;
    float* aggB = (float*)p;             p += AGG_N * 4;
    int* rowptr = (int*)p;               p += 155002L * 4;
    int* cursor = (int*)p;               p += 155002L * 4;   // doubles as counts
    int2* recs = (int2*)p;               p += 900000L * 8;

    // input projections (ReLU)
    gemm64<float, TXS><<<dim3(2, 1563), 256, 0, stream>>>(
        x_paper, lin_w[0], lin_b[0], xs, 100000, 128, 256, 1, (TXS*)nullptr, nullptr, 0);
    gemm64<float, TXS><<<dim3(2, 782), 256, 0, stream>>>(
        x_author, lin_w[1], lin_b[1], xs + 100000L * 128, 50000, 128, 128, 1, (TXS*)nullptr, nullptr, 0);
    gemm64<float, TXS><<<dim3(2, 79), 256, 0, stream>>>(
        x_inst, lin_w[2], lin_b[2], xs + 150000L * 128, 5000, 128, 64, 1, (TXS*)nullptr, nullptr, 0);

    // CSR build (shared by both layers)
    fill_u32<<<(NTOT + 255) / 256, 256, 0, stream>>>((unsigned int*)cursor, 0u, NTOT);
    for (int e = 0; e < 5; e++)
        count_edges<<<(ET_E[e] + 255) / 256, 256, 0, stream>>>(
            ei[e] + ET_E[e], ET_E[e], cursor + TB[ET_dst[e]]);
    scan_excl<<<1, 1024, 0, stream>>>(cursor, rowptr, NTOT);
    copy_u32<<<(NTOT + 255) / 256, 256, 0, stream>>>(rowptr, cursor, NTOT);
    for (int e = 0; e < 5; e++)
        scatter_edges<<<(ET_E[e] + 255) / 256, 256, 0, stream>>>(
            ei[e], ei[e] + ET_E[e], ET_E[e], cursor + TB[ET_dst[e]], recs,
            (int)NPRE[ET_src[e]], ET_ETL[e]);

    // layer 1: output written in-place over xs (skip fused into out-GEMM epilogue)
    TXS* outs1[3] = {xs, xs + 100000L * 128, xs + 150000L * 128};
    hgt_layer_run<TXS, TK, TXS>(stream, ei, xs, kqvB, scB, rowptr, recs, aggB,
                                kqv_w1, kqv_b1, krel1, vrel1, prel1, out_w1, out_b1, skip1,
                                8, 128, true, outs1);

    float* out = (float*)d_out;
    float* outs2[3] = {out, out + 100000L * 64, out + 150000L * 64};
    hgt_layer_run<TXS, TK, float>(stream, ei, xs, kqvB, scB, rowptr, recs, aggB,
                                  kqv_w2, kqv_b2, krel2, vrel2, prel2, out_w2, out_b2, skip2,
                                  4, 64, false, outs2);
}

extern "C" void kernel_launch(void* const* d_in, const int* in_sizes, int n_in,
                              void* d_out, int out_size, void* d_ws, size_t ws_size,
                              hipStream_t stream) {
    const size_t fixed = 4000000UL * 4 + 12800000UL * 4 + 155002UL * 4 * 2 + 900000UL * 8; // sc+agg+csr
    const size_t bytesA = 19840000UL * 4 + 59520000UL * 4 + fixed;  // ~394 MB, all f32
    const size_t bytesB = 19840000UL * 4 + 59520000UL * 2 + fixed;  // ~275 MB, kqv bf16
    if (ws_size >= bytesA) {
        run_model<float, float>(d_in, d_out, d_ws, stream);
    } else if (ws_size >= bytesB) {
        run_model<float, __hip_bfloat16>(d_in, d_out, d_ws, stream);
    } else {
        run_model<__hip_bfloat16, __hip_bfloat16>(d_in, d_out, d_ws, stream);
    }
}

// Round 4
// 2254.035 us; speedup vs baseline: 5.7996x; 1.4331x over previous
//
#include <hip/hip_runtime.h>
#include <hip/hip_bf16.h>
#include <math.h>

// ---------- type helpers ----------
__device__ __forceinline__ float ldf(const float* p) { return *p; }
__device__ __forceinline__ float ldf(const __hip_bfloat16* p) { return __bfloat162float(*p); }
__device__ __forceinline__ void stf(float* p, float v) { *p = v; }
__device__ __forceinline__ void stf(__hip_bfloat16* p, float v) { *p = __float2bfloat16(v); }
__device__ __forceinline__ float gelu1(float v) {
    return 0.5f * v * (1.f + erff(v * 0.70710678118654752f));
}

// ---------- 64x64 register-tiled GEMM: C = act(A@B + bias) (+ gated skip) ----------
template <typename TA, typename TC>
__global__ void gemm64(const TA* __restrict__ A, const float* __restrict__ B,
                       const float* __restrict__ bias, TC* __restrict__ C,
                       int M, int N, int K, int act,
                       const TC* __restrict__ res, const float* __restrict__ skip_arr, int t) {
    __shared__ float As[16][65];
    __shared__ float Bs[16][65];
    int tid = threadIdx.x;
    int tx = tid & 15, ty = tid >> 4;
    int row0 = blockIdx.y * 64, col0 = blockIdx.x * 64;
    float acc[4][4] = {};
    int ar = tid >> 2;
    int ak = (tid & 3) * 4;
    int bk = tid >> 4;
    int bc = (tid & 15) * 4;
    for (int k0 = 0; k0 < K; k0 += 16) {
        int grow = row0 + ar;
        #pragma unroll
        for (int q = 0; q < 4; q++)
            As[ak + q][ar] = (grow < M) ? ldf(A + (long)grow * K + k0 + ak + q) : 0.f;
        #pragma unroll
        for (int q = 0; q < 4; q++)
            Bs[bk][bc + q] = B[(long)(k0 + bk) * N + col0 + bc + q];
        __syncthreads();
        #pragma unroll
        for (int kk = 0; kk < 16; kk++) {
            float a[4], b[4];
            #pragma unroll
            for (int i = 0; i < 4; i++) a[i] = As[kk][ty * 4 + i];
            #pragma unroll
            for (int j = 0; j < 4; j++) b[j] = Bs[kk][tx * 4 + j];
            #pragma unroll
            for (int i = 0; i < 4; i++)
                #pragma unroll
                for (int j = 0; j < 4; j++)
                    acc[i][j] = fmaf(a[i], b[j], acc[i][j]);
        }
        __syncthreads();
    }
    float aval = 0.f;
    if (res != nullptr) { float s = skip_arr[t]; aval = 1.f / (1.f + __expf(-s)); }
    #pragma unroll
    for (int i = 0; i < 4; i++) {
        int row = row0 + ty * 4 + i;
        if (row >= M) continue;
        #pragma unroll
        for (int j = 0; j < 4; j++) {
            int col = col0 + tx * 4 + j;
            float v = acc[i][j] + bias[col];
            if (act == 1) v = fmaxf(v, 0.f);
            if (res != nullptr) v = aval * v + (1.f - aval) * ldf(res + (long)row * N + col);
            stf(C + (long)row * N + col, v);
        }
    }
}

// ---------- small utils ----------
__global__ void fill_u32(unsigned int* __restrict__ p, unsigned int v, int n) {
    int i = blockIdx.x * blockDim.x + threadIdx.x;
    if (i < n) p[i] = v;
}
__global__ void copy_u32(const int* __restrict__ a, int* __restrict__ b, int n) {
    int i = blockIdx.x * blockDim.x + threadIdx.x;
    if (i < n) b[i] = a[i];
}

// ---------- CSR build ----------
__global__ void count_edges(const int* __restrict__ dst, int E, int* __restrict__ counts) {
    int i = blockIdx.x * blockDim.x + threadIdx.x;
    if (i < E) atomicAdd(&counts[dst[i]], 1);
}
__global__ void scan_excl(const int* __restrict__ counts, int* __restrict__ rowptr, int n) {
    __shared__ int sh[1024];
    int carry = 0;
    const int TILE = 8192;
    for (int base = 0; base < n; base += TILE) {
        int lv[8]; int s = 0;
        #pragma unroll
        for (int q = 0; q < 8; q++) {
            int i = base + threadIdx.x * 8 + q;
            lv[q] = (i < n) ? counts[i] : 0;
            s += lv[q];
        }
        sh[threadIdx.x] = s;
        __syncthreads();
        for (int off = 1; off < 1024; off <<= 1) {
            int add = (threadIdx.x >= (unsigned)off) ? sh[threadIdx.x - off] : 0;
            __syncthreads();
            sh[threadIdx.x] += add;
            __syncthreads();
        }
        int excl = sh[threadIdx.x] - s + carry;
        int tot = sh[1023];
        __syncthreads();
        #pragma unroll
        for (int q = 0; q < 8; q++) {
            int i = base + threadIdx.x * 8 + q;
            if (i < n) rowptr[i] = excl;
            excl += lv[q];
        }
        carry += tot;
    }
    if (threadIdx.x == 0) rowptr[n] = carry;
}
__global__ void scatter_edges(const int* __restrict__ src, const int* __restrict__ dst, int E,
                              int* __restrict__ cursor, int2* __restrict__ recs,
                              int srow_base, int etl) {
    int i = blockIdx.x * blockDim.x + threadIdx.x;
    if (i >= E) return;
    int pos = atomicAdd(&cursor[dst[i]], 1);
    recs[pos] = make_int2(srow_base + src[i], (etl << 28) | i);
}

// ---------- relation transform: out[r, h*16+jj] = sum_i in[r, h*16+i] * rel[h,i,jj] ----
// prel!=null folds prel[h]*scale into the matrix (for K; scores then need no extra scaling).
template <typename TK>
__global__ void rel_transform(const TK* __restrict__ in, long in_row_off, int in_stride,
                              int nrows, int H, int fout,
                              const float* __restrict__ rel, const float* __restrict__ prel,
                              float scale, TK* __restrict__ outp) {
    __shared__ float sR[2048];
    int nl = H * 256;
    for (int i = threadIdx.x; i < nl; i += blockDim.x) {
        float f = (prel != nullptr) ? prel[i >> 8] * scale : 1.f;
        sR[i] = rel[i] * f;
    }
    __syncthreads();
    int per = blockDim.x / fout;
    int slot = threadIdx.x / fout;
    int j = threadIdx.x - slot * fout;
    int h = j >> 4;
    const float* rp = sR + h * 256 + (j & 15);
    for (long d = (long)blockIdx.x * per + slot; d < nrows; d += (long)gridDim.x * per) {
        const TK* kp = in + in_row_off + d * in_stride + h * 16;
        float acc = 0.f;
        #pragma unroll
        for (int i = 0; i < 16; i++) acc = fmaf(ldf(kp + i), rp[i * 16], acc);
        stf(outp + d * fout + j, acc);
    }
}

// ---------- scores from precomputed k_rel: sc[e,h] = dot16(q[dst,h], k_rel[src,h]) -----
template <typename TK>
__global__ void edge_score_pre(const TK* __restrict__ krelbuf, int ro, const TK* __restrict__ Qdst,
                               int stride, int H, int fout,
                               const int* __restrict__ src, const int* __restrict__ dst, int E,
                               float* __restrict__ sc_out) {
    long tid = blockIdx.x * (long)blockDim.x + threadIdx.x;
    if (tid >= (long)E * H) return;
    int e = (int)(tid / H);
    int h = (int)(tid - (long)e * H);
    const TK* kp = krelbuf + ((long)ro + src[e]) * fout + h * 16;
    const TK* qp = Qdst + (long)dst[e] * stride + h * 16;
    float acc = 0.f;
    #pragma unroll
    for (int i = 0; i < 16; i++) acc = fmaf(ldf(kp + i), ldf(qp + i), acc);
    sc_out[tid] = acc;
}

// ---------- scores with on-the-fly k_rel (MID/FB paths) ----------
template <typename TK>
__global__ void edge_score(const TK* __restrict__ Ksrc, const TK* __restrict__ Qdst,
                           int stride, int H,
                           const int* __restrict__ src, const int* __restrict__ dst, int E,
                           const float* __restrict__ krel, const float* __restrict__ prel,
                           float scale, float* __restrict__ sc_out) {
    __shared__ float sM[2048];
    __shared__ float sP[8];
    int nload = H * 256;
    for (int i = threadIdx.x; i < nload; i += blockDim.x) sM[i] = krel[i];
    if ((int)threadIdx.x < H) sP[threadIdx.x] = prel[threadIdx.x];
    __syncthreads();
    long tid = blockIdx.x * (long)blockDim.x + threadIdx.x;
    if (tid >= (long)E * H) return;
    int e = (int)(tid / H);
    int h = (int)(tid - (long)e * H);
    int s = src[e], d = dst[e];
    const TK* kp = Ksrc + (long)s * stride + h * 16;
    const TK* qp = Qdst + (long)d * stride + h * 16;
    const float* km = sM + h * 256;
    float kv[16];
    #pragma unroll
    for (int i = 0; i < 16; i++) kv[i] = ldf(kp + i);
    float acc = 0.f;
    #pragma unroll
    for (int j = 0; j < 16; j++) {
        float kr = 0.f;
        #pragma unroll
        for (int i = 0; i < 16; i++) kr = fmaf(kv[i], km[i * 16 + j], kr);
        acc = fmaf(kr, ldf(qp + j), acc);
    }
    sc_out[tid] = acc * sP[h] * scale;
}

// ---------- fused online-softmax + gather of precomputed v_rel (no LDS, no shuffles) ----
// 256-thread block covers (256/fout) dst nodes; thread j handles output dim j of its dst.
template <typename TK>
__global__ void gather_agg_pre(const TK* __restrict__ vrelbuf, int H, int fout,
                               const int2* __restrict__ recs, const int* __restrict__ rowptr,
                               int tb, int ndst,
                               const float* __restrict__ sc, int sb0, int sb1,
                               int ro0, int ro1, int nb0, int nb1,
                               float* __restrict__ agg) {
    int per = blockDim.x / fout;
    int slot = threadIdx.x / fout;
    int j = threadIdx.x - slot * fout;
    int d = blockIdx.x * per + slot;
    if (d >= ndst) return;
    int h = j >> 4;
    int r0 = rowptr[tb + d], r1 = rowptr[tb + d + 1];
    float m = -1e30f, l = 0.f, acc = 0.f;
    for (int idx = r0; idx < r1; ++idx) {
        int2 rec = recs[idx];
        int etl = rec.y >> 28;
        int ei = rec.y & 0x0FFFFFFF;
        float s = sc[(long)(etl ? sb1 : sb0) + (long)ei * H + h];
        long row = (etl ? ro1 : ro0) + (long)(rec.x - (etl ? nb1 : nb0));
        float vv = ldf(vrelbuf + row * fout + j);
        float mn = fmaxf(m, s);
        float r = __expf(m - mn);
        float w = __expf(s - mn);
        acc = fmaf(acc, r, w * vv);
        l = fmaf(l, r, w);
        m = mn;
    }
    float res = (l > 0.f) ? acc / l : 0.f;
    agg[(long)d * fout + j] = gelu1(res);
}

// ---------- fallback gather (R3 version, used only if workspace is tight) ----------
template <typename TK>
__global__ void gather_agg(const TK* __restrict__ kqv, int F3, int H, int fout,
                           const int2* __restrict__ recs, const int* __restrict__ rowptr, int tb,
                           const float* __restrict__ sc, int sb0, int sb1,
                           const float* __restrict__ vrel0, const float* __restrict__ vrel1,
                           float* __restrict__ agg) {
    __shared__ float sV[4096];
    int nv = H * 256;
    for (int i = threadIdx.x; i < nv; i += blockDim.x) {
        sV[i] = vrel0[i];
        sV[nv + i] = vrel1[i];
    }
    __syncthreads();
    int d = blockIdx.x;
    int r0 = rowptr[tb + d], r1 = rowptr[tb + d + 1];
    int deg = r1 - r0;
    int j = threadIdx.x;
    if (deg == 0) { agg[(long)d * fout + j] = 0.f; return; }
    int h = j >> 4, jj = j & 15;
    float m = -1e30f, l = 0.f;
    for (int idx = jj; idx < deg; idx += 16) {
        int2 rec = recs[r0 + idx];
        int etl = rec.y >> 28;
        int ei = rec.y & 0x0FFFFFFF;
        float v = sc[(etl ? sb1 : sb0) + ei * H + h];
        float mn = fmaxf(m, v);
        l = l * __expf(m - mn) + __expf(v - mn);
        m = mn;
    }
    #pragma unroll
    for (int off = 1; off < 16; off <<= 1) {
        float mo = __shfl_xor(m, off, 64);
        float lo = __shfl_xor(l, off, 64);
        float mn = fmaxf(m, mo);
        l = l * __expf(m - mn) + lo * __expf(mo - mn);
        m = mn;
    }
    float invden = 1.f / fmaxf(l, 1e-16f);
    const TK* vbase = kqv + 2 * fout;
    int gbase = (j & 63) & ~15;
    float acc = 0.f;
    for (int idx = 0; idx < deg; ++idx) {
        int2 rec = recs[r0 + idx];
        int srow = rec.x;
        int etl = rec.y >> 28;
        int ei = rec.y & 0x0FFFFFFF;
        float alpha = __expf(sc[(etl ? sb1 : sb0) + ei * H + h] - m) * invden;
        float vv = ldf(vbase + (long)srow * F3 + j);
        const float* vmp = sV + (etl ? nv : 0) + h * 256 + jj;
        float vr = 0.f;
        #pragma unroll
        for (int i = 0; i < 16; i++) {
            float vi = __shfl(vv, gbase + i, 64);
            vr = fmaf(vi, vmp[i * 16], vr);
        }
        acc = fmaf(alpha, vr, acc);
    }
    agg[(long)d * fout + j] = gelu1(acc);
}

// ---------- orchestration ----------
static const int ET_src[5] = {1, 0, 0, 1, 2};
static const int ET_dst[5] = {0, 0, 1, 2, 1};
static const int ET_E[5]   = {250000, 250000, 200000, 100000, 100000};
static const int NT[3]     = {100000, 50000, 5000};
static const long NPRE[3]  = {0, 100000, 150000};
static const int TB[3]     = {0, 100000, 150000};
static const int NTOT      = 155000;

template <typename TXS, typename TK, typename TO>
static void hgt_layer_run(hipStream_t stream, const int* const* ei,
                          const TXS* xs, TK* kqvB, float* scB,
                          const int* rowptr, const int2* recs, float* aggB,
                          TK* krelB, TK* vrelB, int mode,
                          const float* kqv_w, const float* kqv_b, const float* krel,
                          const float* vrel, const float* prel, const float* out_w,
                          const float* out_b, const float* skip_arr,
                          int H, int fout, bool do_skip, TO* const* outs) {
    const int F3 = 3 * fout;
    for (int t = 0; t < 3; t++) {
        dim3 grid(F3 / 64, (NT[t] + 63) / 64);
        gemm64<TXS, TK><<<grid, 256, 0, stream>>>(
            xs + NPRE[t] * 128, kqv_w + (long)t * 128 * F3, kqv_b + t * F3,
            kqvB + NPRE[t] * F3, NT[t], F3, 128, 0, (TK*)nullptr, nullptr, 0);
    }
    for (int t = 0; t < 3; t++) {
        int el[2], ne = 0;
        for (int e = 0; e < 5; e++) if (ET_dst[e] == t) el[ne++] = e;
        long scoff = 0;
        int sb[2] = {0, 0}, ro[2] = {0, 0}, nb[2] = {0, 0};
        const float* vr[2] = {vrel, vrel};
        int rocur = 0;
        for (int i = 0; i < ne; i++) {
            int e = el[i], ts = ET_src[e];
            int E = ET_E[e];
            long tot = (long)E * H;
            sb[i] = (int)scoff; ro[i] = rocur; nb[i] = (int)NPRE[ts];
            vr[i] = vrel + (long)e * H * 256;
            if (mode >= 1) {
                int per = 256 / fout;
                int tg = (NT[ts] + per - 1) / per; if (tg > 1024) tg = 1024;
                rel_transform<TK><<<tg, 256, 0, stream>>>(
                    kqvB, NPRE[ts] * F3 + 2 * fout, F3, NT[ts], H, fout,
                    vrel + (long)e * H * 256, nullptr, 1.f, vrelB + (long)rocur * fout);
                if (mode == 2) {
                    rel_transform<TK><<<tg, 256, 0, stream>>>(
                        kqvB, NPRE[ts] * F3, F3, NT[ts], H, fout,
                        krel + (long)e * H * 256, prel + e * H, 0.25f,
                        krelB + (long)rocur * fout);
                }
            }
            if (mode == 2) {
                edge_score_pre<TK><<<(int)((tot + 255) / 256), 256, 0, stream>>>(
                    krelB, ro[i], kqvB + NPRE[t] * F3 + fout, F3, H, fout,
                    ei[e], ei[e] + E, E, scB + scoff);
            } else {
                edge_score<TK><<<(int)((tot + 255) / 256), 256, 0, stream>>>(
                    kqvB + NPRE[ts] * F3, kqvB + NPRE[t] * F3 + fout, F3, H,
                    ei[e], ei[e] + E, E, krel + (long)e * H * 256, prel + e * H, 0.25f,
                    scB + scoff);
            }
            scoff += tot;
            rocur += NT[ts];
        }
        if (ne == 1) { sb[1] = sb[0]; ro[1] = ro[0]; nb[1] = nb[0]; vr[1] = vr[0]; }
        if (mode >= 1) {
            int per = 256 / fout;
            gather_agg_pre<TK><<<(NT[t] + per - 1) / per, 256, 0, stream>>>(
                vrelB, H, fout, recs, rowptr, TB[t], NT[t],
                scB, sb[0], sb[1], ro[0], ro[1], nb[0], nb[1], aggB);
        } else {
            gather_agg<TK><<<NT[t], fout, 0, stream>>>(
                kqvB, F3, H, fout, recs, rowptr, TB[t], scB, sb[0], sb[1], vr[0], vr[1], aggB);
        }
        dim3 grid2(fout / 64, (NT[t] + 63) / 64);
        gemm64<float, TO><<<grid2, 256, 0, stream>>>(
            aggB, out_w + (long)t * fout * fout, out_b + t * fout, outs[t],
            NT[t], fout, fout, 0,
            do_skip ? outs[t] : (TO*)nullptr, skip_arr, t);
    }
}

template <typename TXS, typename TK>
static void run_model(void* const* d_in, void* d_out, void* d_ws, int mode, hipStream_t stream) {
    const float* x_paper  = (const float*)d_in[0];
    const float* x_author = (const float*)d_in[1];
    const float* x_inst   = (const float*)d_in[2];
    const int* ei[5];
    for (int e = 0; e < 5; e++) ei[e] = (const int*)d_in[3 + e];
    const float* lin_w[3] = {(const float*)d_in[8], (const float*)d_in[10], (const float*)d_in[12]};
    const float* lin_b[3] = {(const float*)d_in[9], (const float*)d_in[11], (const float*)d_in[13]};
    const float* kqv_w1 = (const float*)d_in[14];
    const float* kqv_b1 = (const float*)d_in[15];
    const float* krel1  = (const float*)d_in[16];
    const float* vrel1  = (const float*)d_in[17];
    const float* prel1  = (const float*)d_in[18];
    const float* out_w1 = (const float*)d_in[19];
    const float* out_b1 = (const float*)d_in[20];
    const float* skip1  = (const float*)d_in[21];
    const float* kqv_w2 = (const float*)d_in[22];
    const float* kqv_b2 = (const float*)d_in[23];
    const float* krel2  = (const float*)d_in[24];
    const float* vrel2  = (const float*)d_in[25];
    const float* prel2  = (const float*)d_in[26];
    const float* out_w2 = (const float*)d_in[27];
    const float* out_b2 = (const float*)d_in[28];
    const float* skip2  = (const float*)d_in[29];

    // workspace carve: xs, kqv, sc, agg, csr, vrel(per-t), krel(per-t)
    const long XS_N = 19840000L, KQV_N = 59520000L, SC_N = 4000000L, AGG_N = 12800000L;
    const long REL_N = 19200000L;  // 150k rows x 128
    char* p = (char*)d_ws;
    TXS* xs = (TXS*)p;                   p += XS_N * sizeof(TXS);
    TK* kqvB = (TK*)p;                   p += KQV_N * sizeof(TK);
    float* scB = (float*)p;              p += SC_N * 4;
    float* aggB = (float*)p;             p += AGG_N * 4;
    int* rowptr = (int*)p;               p += 155002L * 4;
    int* cursor = (int*)p;               p += 155002L * 4;
    int2* recs = (int2*)p;               p += 900000L * 8;
    TK* vrelB = (TK*)p;                  p += REL_N * sizeof(TK);
    TK* krelB = (TK*)p;

    // input projections (ReLU)
    gemm64<float, TXS><<<dim3(2, 1563), 256, 0, stream>>>(
        x_paper, lin_w[0], lin_b[0], xs, 100000, 128, 256, 1, (TXS*)nullptr, nullptr, 0);
    gemm64<float, TXS><<<dim3(2, 782), 256, 0, stream>>>(
        x_author, lin_w[1], lin_b[1], xs + 100000L * 128, 50000, 128, 128, 1, (TXS*)nullptr, nullptr, 0);
    gemm64<float, TXS><<<dim3(2, 79), 256, 0, stream>>>(
        x_inst, lin_w[2], lin_b[2], xs + 150000L * 128, 5000, 128, 64, 1, (TXS*)nullptr, nullptr, 0);

    // CSR build (shared by both layers)
    fill_u32<<<(NTOT + 255) / 256, 256, 0, stream>>>((unsigned int*)cursor, 0u, NTOT);
    for (int e = 0; e < 5; e++)
        count_edges<<<(ET_E[e] + 255) / 256, 256, 0, stream>>>(
            ei[e] + ET_E[e], ET_E[e], cursor + TB[ET_dst[e]]);
    scan_excl<<<1, 1024, 0, stream>>>(cursor, rowptr, NTOT);
    copy_u32<<<(NTOT + 255) / 256, 256, 0, stream>>>(rowptr, cursor, NTOT);
    static const int ET_ETL[5] = {0, 1, 0, 0, 1};
    for (int e = 0; e < 5; e++)
        scatter_edges<<<(ET_E[e] + 255) / 256, 256, 0, stream>>>(
            ei[e], ei[e] + ET_E[e], ET_E[e], cursor + TB[ET_dst[e]], recs,
            (int)NPRE[ET_src[e]], ET_ETL[e]);

    // layer 1 (output in-place over xs; gated skip fused into out-GEMM)
    TXS* outs1[3] = {xs, xs + 100000L * 128, xs + 150000L * 128};
    hgt_layer_run<TXS, TK, TXS>(stream, ei, xs, kqvB, scB, rowptr, recs, aggB, krelB, vrelB, mode,
                                kqv_w1, kqv_b1, krel1, vrel1, prel1, out_w1, out_b1, skip1,
                                8, 128, true, outs1);

    float* out = (float*)d_out;
    float* outs2[3] = {out, out + 100000L * 64, out + 150000L * 64};
    hgt_layer_run<TXS, TK, float>(stream, ei, xs, kqvB, scB, rowptr, recs, aggB, krelB, vrelB, mode,
                                  kqv_w2, kqv_b2, krel2, vrel2, prel2, out_w2, out_b2, skip2,
                                  4, 64, false, outs2);
}

extern "C" void kernel_launch(void* const* d_in, const int* in_sizes, int n_in,
                              void* d_out, int out_size, void* d_ws, size_t ws_size,
                              hipStream_t stream) {
    // tiers (ws_size constant across calls -> graph-stable branch):
    //   BIG  ~351 MB: xs f32, kqv bf16, K_rel+V_rel precomputed (mode 2)
    //   MID  ~273 MB: xs bf16, kqv bf16, V_rel precomputed, K on the fly (mode 1)
    //   FB   ~234 MB: R3 structure, all-LDS gather (mode 0)
    if (ws_size >= 352000000UL) {
        run_model<float, __hip_bfloat16>(d_in, d_out, d_ws, 2, stream);
    } else if (ws_size >= 274000000UL) {
        run_model<__hip_bfloat16, __hip_bfloat16>(d_in, d_out, d_ws, 1, stream);
    } else {
        run_model<__hip_bfloat16, __hip_bfloat16>(d_in, d_out, d_ws, 0, stream);
    }
}

// Round 5
// 2083.550 us; speedup vs baseline: 6.2742x; 1.0818x over previous
//
#include <hip/hip_runtime.h>
#include <hip/hip_bf16.h>
#include <math.h>

typedef __attribute__((ext_vector_type(8))) short short8;
typedef __attribute__((ext_vector_type(4))) short short4v;
typedef __attribute__((ext_vector_type(4))) float floatx4;

// ---------- type helpers ----------
__device__ __forceinline__ float ldf(const float* p) { return *p; }
__device__ __forceinline__ float ldf(const __hip_bfloat16* p) { return __bfloat162float(*p); }
__device__ __forceinline__ void stf(float* p, float v) { *p = v; }
__device__ __forceinline__ void stf(__hip_bfloat16* p, float v) { *p = __float2bfloat16(v); }
__device__ __forceinline__ float gelu1(float v) {
    return 0.5f * v * (1.f + erff(v * 0.70710678118654752f));
}
__device__ __forceinline__ short f2bf(float f) {
    unsigned int u = __float_as_uint(f);
    unsigned int r = (u + 0x7FFFu + ((u >> 16) & 1u)) >> 16;
    return (short)r;
}
__device__ __forceinline__ void load16bf(const __hip_bfloat16* p, float* o) {
    const uint4* u = (const uint4*)p;
    uint4 w0 = u[0], w1 = u[1];
    unsigned int ws[8] = {w0.x, w0.y, w0.z, w0.w, w1.x, w1.y, w1.z, w1.w};
    #pragma unroll
    for (int i = 0; i < 8; i++) {
        o[2 * i]     = __uint_as_float(ws[i] << 16);
        o[2 * i + 1] = __uint_as_float(ws[i] & 0xFFFF0000u);
    }
}

// ---------- weight pack: W[K,N] f32 -> Wt[N,K] bf16 (batched over grid.z) ----------
__global__ void pack_wt(const float* __restrict__ W, __hip_bfloat16* __restrict__ Wt,
                        int K, int N) {
    __shared__ float tile[32][33];
    long b = blockIdx.z;
    const float* Wb = W + b * K * N;
    __hip_bfloat16* Wtb = Wt + b * K * N;
    int k0 = blockIdx.y * 32, n0 = blockIdx.x * 32;
    int tx = threadIdx.x, ty = threadIdx.y;  // 32 x 8
    #pragma unroll
    for (int i = 0; i < 32; i += 8) {
        int k = k0 + ty + i, n = n0 + tx;
        tile[ty + i][tx] = (k < K && n < N) ? Wb[(long)k * N + n] : 0.f;
    }
    __syncthreads();
    #pragma unroll
    for (int i = 0; i < 32; i += 8) {
        int n = n0 + ty + i, k = k0 + tx;
        if (n < N && k < K) Wtb[(long)n * K + k] = __float2bfloat16(tile[tx][ty + i]);
    }
}

// ---------- MFMA GEMM: C[M,N] = act(A[M,K]f32 @ B + bias) (+ gated skip) ----------
// Bt[N,K] bf16 pre-transposed. N%64==0, K%64==0. Block=128 thr (2 waves),
// BM=128 BN=64 BK=64; wave w covers rows w*64..+63, all 64 cols (4x4 mfma tiles).
template <typename TC>
__global__ __launch_bounds__(128)
void gemm_mfma(const float* __restrict__ A, const __hip_bfloat16* __restrict__ Bt,
               const float* __restrict__ bias, TC* __restrict__ C,
               int M, int N, int K, int act,
               const TC* __restrict__ res, const float* __restrict__ skip_arr, int t) {
    __shared__ short As[128][72];  // +8 pad: 2-way bank alias only (free)
    __shared__ short Bs[64][72];
    int tid = threadIdx.x;
    int row0 = blockIdx.y * 128, col0 = blockIdx.x * 64;
    int wave = tid >> 6, lane = tid & 63;
    int wm = wave * 64;
    int lm = lane & 15, kg = lane >> 4;
    floatx4 acc[4][4];
    #pragma unroll
    for (int i = 0; i < 4; i++)
        #pragma unroll
        for (int j = 0; j < 4; j++) acc[i][j] = floatx4{0.f, 0.f, 0.f, 0.f};

    for (int k0 = 0; k0 < K; k0 += 64) {
        for (int p = 0; p < 16; p++) {
            int q = p * 128 + tid;
            int r = q >> 4, c = (q & 15) * 4;
            int grow = row0 + r;
            float4 v = make_float4(0.f, 0.f, 0.f, 0.f);
            if (grow < M) v = *(const float4*)(A + (long)grow * K + k0 + c);
            short4v s;
            s.x = f2bf(v.x); s.y = f2bf(v.y); s.z = f2bf(v.z); s.w = f2bf(v.w);
            *(short4v*)&As[r][c] = s;
        }
        #pragma unroll
        for (int p = 0; p < 4; p++) {
            int q = p * 128 + tid;
            int r = q >> 3, c = (q & 7) * 8;
            *(short8*)&Bs[r][c] = *(const short8*)(Bt + (long)(col0 + r) * K + k0 + c);
        }
        __syncthreads();
        #pragma unroll
        for (int kk = 0; kk < 2; kk++) {
            int kb = kk * 32 + kg * 8;
            short8 a[4], b[4];
            #pragma unroll
            for (int mt = 0; mt < 4; mt++) a[mt] = *(short8*)&As[wm + mt * 16 + lm][kb];
            #pragma unroll
            for (int nt = 0; nt < 4; nt++) b[nt] = *(short8*)&Bs[nt * 16 + lm][kb];
            #pragma unroll
            for (int mt = 0; mt < 4; mt++)
                #pragma unroll
                for (int nt = 0; nt < 4; nt++)
                    acc[mt][nt] = __builtin_amdgcn_mfma_f32_16x16x32_bf16(
                        a[mt], b[nt], acc[mt][nt], 0, 0, 0);
        }
        __syncthreads();
    }
    float aval = 0.f;
    bool do_res = (res != nullptr);
    if (do_res) { float s = skip_arr[t]; aval = 1.f / (1.f + __expf(-s)); }
    int rg = (lane >> 4) * 4;  // C/D: col=lane&15, row=(lane>>4)*4+reg
    #pragma unroll
    for (int mt = 0; mt < 4; mt++) {
        #pragma unroll
        for (int nt = 0; nt < 4; nt++) {
            int col = col0 + nt * 16 + lm;
            float bsv = bias[col];
            #pragma unroll
            for (int r = 0; r < 4; r++) {
                int row = row0 + wm + mt * 16 + rg + r;
                if (row < M) {
                    float v = acc[mt][nt][r] + bsv;
                    if (act == 1) v = fmaxf(v, 0.f);
                    if (do_res) v = aval * v + (1.f - aval) * ldf(res + (long)row * N + col);
                    stf(C + (long)row * N + col, v);
                }
            }
        }
    }
}

// ---------- small utils ----------
__global__ void fill_u32(unsigned int* __restrict__ p, unsigned int v, int n) {
    int i = blockIdx.x * blockDim.x + threadIdx.x;
    if (i < n) p[i] = v;
}
__global__ void copy_u32(const int* __restrict__ a, int* __restrict__ b, int n) {
    int i = blockIdx.x * blockDim.x + threadIdx.x;
    if (i < n) b[i] = a[i];
}

// ---------- CSR build ----------
__global__ void count_edges(const int* __restrict__ dst, int E, int* __restrict__ counts) {
    int i = blockIdx.x * blockDim.x + threadIdx.x;
    if (i < E) atomicAdd(&counts[dst[i]], 1);
}
__global__ void scan_excl(const int* __restrict__ counts, int* __restrict__ rowptr, int n) {
    __shared__ int sh[1024];
    int carry = 0;
    const int TILE = 8192;
    for (int base = 0; base < n; base += TILE) {
        int lv[8]; int s = 0;
        #pragma unroll
        for (int q = 0; q < 8; q++) {
            int i = base + threadIdx.x * 8 + q;
            lv[q] = (i < n) ? counts[i] : 0;
            s += lv[q];
        }
        sh[threadIdx.x] = s;
        __syncthreads();
        for (int off = 1; off < 1024; off <<= 1) {
            int add = (threadIdx.x >= (unsigned)off) ? sh[threadIdx.x - off] : 0;
            __syncthreads();
            sh[threadIdx.x] += add;
            __syncthreads();
        }
        int excl = sh[threadIdx.x] - s + carry;
        int tot = sh[1023];
        __syncthreads();
        #pragma unroll
        for (int q = 0; q < 8; q++) {
            int i = base + threadIdx.x * 8 + q;
            if (i < n) rowptr[i] = excl;
            excl += lv[q];
        }
        carry += tot;
    }
    if (threadIdx.x == 0) rowptr[n] = carry;
}
__global__ void scatter_edges(const int* __restrict__ src, const int* __restrict__ dst, int E,
                              int* __restrict__ cursor, int2* __restrict__ recs,
                              int srow_base, int etl) {
    int i = blockIdx.x * blockDim.x + threadIdx.x;
    if (i >= E) return;
    int pos = atomicAdd(&cursor[dst[i]], 1);
    recs[pos] = make_int2(srow_base + src[i], (etl << 28) | i);
}

// ---------- relation transform ----------
__global__ void rel_transform(const __hip_bfloat16* __restrict__ in, long in_row_off,
                              int in_stride, int nrows, int H, int fout,
                              const float* __restrict__ rel, const float* __restrict__ prel,
                              float scale, __hip_bfloat16* __restrict__ outp) {
    __shared__ float sR[2048];
    int nl = H * 256;
    for (int i = threadIdx.x; i < nl; i += blockDim.x) {
        float f = (prel != nullptr) ? prel[i >> 8] * scale : 1.f;
        sR[i] = rel[i] * f;
    }
    __syncthreads();
    int per = blockDim.x / fout;
    int slot = threadIdx.x / fout;
    int j = threadIdx.x - slot * fout;
    int h = j >> 4;
    const float* rp = sR + h * 256 + (j & 15);
    for (long d = (long)blockIdx.x * per + slot; d < nrows; d += (long)gridDim.x * per) {
        float xv[16];
        load16bf(in + in_row_off + d * in_stride + h * 16, xv);
        float acc = 0.f;
        #pragma unroll
        for (int i = 0; i < 16; i++) acc = fmaf(xv[i], rp[i * 16], acc);
        outp[d * fout + j] = __float2bfloat16(acc);
    }
}

// ---------- scores from precomputed k_rel ----------
__global__ void edge_score_pre(const __hip_bfloat16* __restrict__ krelbuf, int ro,
                               const __hip_bfloat16* __restrict__ Qdst,
                               int stride, int H, int fout,
                               const int* __restrict__ src, const int* __restrict__ dst, int E,
                               float* __restrict__ sc_out) {
    long tid = blockIdx.x * (long)blockDim.x + threadIdx.x;
    if (tid >= (long)E * H) return;
    int e = (int)(tid / H);
    int h = (int)(tid - (long)e * H);
    float kv[16], qv[16];
    load16bf(krelbuf + ((long)ro + src[e]) * fout + h * 16, kv);
    load16bf(Qdst + (long)dst[e] * stride + h * 16, qv);
    float acc = 0.f;
    #pragma unroll
    for (int i = 0; i < 16; i++) acc = fmaf(kv[i], qv[i], acc);
    sc_out[tid] = acc;
}

// ---------- fused online-softmax + gather of precomputed v_rel ----------
__global__ void gather_agg_pre(const __hip_bfloat16* __restrict__ vrelbuf, int H, int fout,
                               const int2* __restrict__ recs, const int* __restrict__ rowptr,
                               int tb, int ndst,
                               const float* __restrict__ sc, int sb0, int sb1,
                               int ro0, int ro1, int nb0, int nb1,
                               float* __restrict__ agg) {
    int per = blockDim.x / fout;
    int slot = threadIdx.x / fout;
    int j = threadIdx.x - slot * fout;
    int d = blockIdx.x * per + slot;
    if (d >= ndst) return;
    int h = j >> 4;
    int r0 = rowptr[tb + d], r1 = rowptr[tb + d + 1];
    float m = -1e30f, l = 0.f, acc = 0.f;
    for (int idx = r0; idx < r1; ++idx) {
        int2 rec = recs[idx];
        int etl = rec.y >> 28;
        int ei = rec.y & 0x0FFFFFFF;
        float s = sc[(long)(etl ? sb1 : sb0) + (long)ei * H + h];
        long row = (etl ? ro1 : ro0) + (long)(rec.x - (etl ? nb1 : nb0));
        float vv = ldf(vrelbuf + row * fout + j);
        float mn = fmaxf(m, s);
        float r = __expf(m - mn);
        float w = __expf(s - mn);
        acc = fmaf(acc, r, w * vv);
        l = fmaf(l, r, w);
        m = mn;
    }
    float res = (l > 0.f) ? acc / l : 0.f;
    agg[(long)d * fout + j] = gelu1(res);
}

// ---------- orchestration ----------
static const int ET_src[5] = {1, 0, 0, 1, 2};
static const int ET_dst[5] = {0, 0, 1, 2, 1};
static const int ET_E[5]   = {250000, 250000, 200000, 100000, 100000};
static const int NT[3]     = {100000, 50000, 5000};
static const long NPRE[3]  = {0, 100000, 150000};
static const int TB[3]     = {0, 100000, 150000};
static const int NTOT      = 155000;

template <typename TO>
static void hgt_layer_run(hipStream_t stream, const int* const* ei,
                          const float* xs, __hip_bfloat16* kqvB, float* scB,
                          const int* rowptr, const int2* recs, float* aggB,
                          __hip_bfloat16* krelB, __hip_bfloat16* vrelB,
                          const __hip_bfloat16* wt_kqv, const float* kqv_b,
                          const float* krel, const float* vrel, const float* prel,
                          const __hip_bfloat16* wt_out, const float* out_b,
                          const float* skip_arr,
                          int H, int fout, bool do_skip, TO* const* outs) {
    const int F3 = 3 * fout;
    for (int t = 0; t < 3; t++) {
        dim3 grid(F3 / 64, (NT[t] + 127) / 128);
        gemm_mfma<__hip_bfloat16><<<grid, 128, 0, stream>>>(
            xs + NPRE[t] * 128, wt_kqv + (long)t * 128 * F3, kqv_b + t * F3,
            kqvB + NPRE[t] * F3, NT[t], F3, 128, 0,
            (__hip_bfloat16*)nullptr, nullptr, 0);
    }
    for (int t = 0; t < 3; t++) {
        int el[2], ne = 0;
        for (int e = 0; e < 5; e++) if (ET_dst[e] == t) el[ne++] = e;
        long scoff = 0;
        int sb[2] = {0, 0}, ro[2] = {0, 0}, nb[2] = {0, 0};
        int rocur = 0;
        for (int i = 0; i < ne; i++) {
            int e = el[i], ts = ET_src[e];
            int E = ET_E[e];
            long tot = (long)E * H;
            sb[i] = (int)scoff; ro[i] = rocur; nb[i] = (int)NPRE[ts];
            int per = 256 / fout;
            int tg = (NT[ts] + per - 1) / per; if (tg > 2048) tg = 2048;
            rel_transform<<<tg, 256, 0, stream>>>(
                kqvB, NPRE[ts] * F3 + 2 * fout, F3, NT[ts], H, fout,
                vrel + (long)e * H * 256, nullptr, 1.f, vrelB + (long)rocur * fout);
            rel_transform<<<tg, 256, 0, stream>>>(
                kqvB, NPRE[ts] * F3, F3, NT[ts], H, fout,
                krel + (long)e * H * 256, prel + e * H, 0.25f,
                krelB + (long)rocur * fout);
            edge_score_pre<<<(int)((tot + 255) / 256), 256, 0, stream>>>(
                krelB, ro[i], kqvB + NPRE[t] * F3 + fout, F3, H, fout,
                ei[e], ei[e] + E, E, scB + scoff);
            scoff += tot;
            rocur += NT[ts];
        }
        if (ne == 1) { sb[1] = sb[0]; ro[1] = ro[0]; nb[1] = nb[0]; }
        int per = 256 / fout;
        gather_agg_pre<<<(NT[t] + per - 1) / per, 256, 0, stream>>>(
            vrelB, H, fout, recs, rowptr, TB[t], NT[t],
            scB, sb[0], sb[1], ro[0], ro[1], nb[0], nb[1], aggB);
        dim3 grid2(fout / 64, (NT[t] + 127) / 128);
        gemm_mfma<TO><<<grid2, 128, 0, stream>>>(
            aggB, wt_out + (long)t * fout * fout, out_b + t * fout, outs[t],
            NT[t], fout, fout, 0,
            do_skip ? outs[t] : (TO*)nullptr, skip_arr, t);
    }
}

extern "C" void kernel_launch(void* const* d_in, const int* in_sizes, int n_in,
                              void* d_out, int out_size, void* d_ws, size_t ws_size,
                              hipStream_t stream) {
    const float* x_paper  = (const float*)d_in[0];
    const float* x_author = (const float*)d_in[1];
    const float* x_inst   = (const float*)d_in[2];
    const int* ei[5];
    for (int e = 0; e < 5; e++) ei[e] = (const int*)d_in[3 + e];
    const float* lin_w[3] = {(const float*)d_in[8], (const float*)d_in[10], (const float*)d_in[12]};
    const float* lin_b[3] = {(const float*)d_in[9], (const float*)d_in[11], (const float*)d_in[13]};
    const float* kqv_w1 = (const float*)d_in[14];
    const float* kqv_b1 = (const float*)d_in[15];
    const float* krel1  = (const float*)d_in[16];
    const float* vrel1  = (const float*)d_in[17];
    const float* prel1  = (const float*)d_in[18];
    const float* out_w1 = (const float*)d_in[19];
    const float* out_b1 = (const float*)d_in[20];
    const float* skip1  = (const float*)d_in[21];
    const float* kqv_w2 = (const float*)d_in[22];
    const float* kqv_b2 = (const float*)d_in[23];
    const float* krel2  = (const float*)d_in[24];
    const float* vrel2  = (const float*)d_in[25];
    const float* prel2  = (const float*)d_in[26];
    const float* out_w2 = (const float*)d_in[27];
    const float* out_b2 = (const float*)d_in[28];
    const float* skip2  = (const float*)d_in[29];

    // workspace carve (all offsets 16B-aligned); total 351,520,000 B (<= ws, >=352MB per R4)
    char* p = (char*)d_ws;
    float* xs = (float*)p;                      p += 19840000L * 4;
    __hip_bfloat16* kqvB = (__hip_bfloat16*)p;  p += 59520000L * 2;
    float* scB = (float*)p;                     p += 4000000L * 4;
    float* aggB = (float*)p;                    p += 12800000L * 4;
    int* rowptr = (int*)p;                      p += 155008L * 4;
    int* cursor = (int*)p;                      p += 155008L * 4;
    int2* recs = (int2*)p;                      p += 900000L * 8;
    __hip_bfloat16* vrelB = (__hip_bfloat16*)p; p += 19200000L * 2;
    __hip_bfloat16* krelB = (__hip_bfloat16*)p; p += 19200000L * 2;
    __hip_bfloat16* wtA = (__hip_bfloat16*)p;

    __hip_bfloat16* wt_lin[3] = {wtA, wtA + 32768, wtA + 49152};
    __hip_bfloat16* wt_kqv1 = wtA + 57344;
    __hip_bfloat16* wt_out1 = wtA + 204800;
    __hip_bfloat16* wt_kqv2 = wtA + 253952;
    __hip_bfloat16* wt_out2 = wtA + 327680;

    dim3 pb(32, 8);
    pack_wt<<<dim3(4, 8, 1), pb, 0, stream>>>(lin_w[0], wt_lin[0], 256, 128);
    pack_wt<<<dim3(4, 4, 1), pb, 0, stream>>>(lin_w[1], wt_lin[1], 128, 128);
    pack_wt<<<dim3(4, 2, 1), pb, 0, stream>>>(lin_w[2], wt_lin[2], 64, 128);
    pack_wt<<<dim3(12, 4, 3), pb, 0, stream>>>(kqv_w1, wt_kqv1, 128, 384);
    pack_wt<<<dim3(4, 4, 3), pb, 0, stream>>>(out_w1, wt_out1, 128, 128);
    pack_wt<<<dim3(6, 4, 3), pb, 0, stream>>>(kqv_w2, wt_kqv2, 128, 192);
    pack_wt<<<dim3(2, 2, 3), pb, 0, stream>>>(out_w2, wt_out2, 64, 64);

    // input projections (ReLU). N=128 for all; K = 256 / 128 / 64.
    gemm_mfma<float><<<dim3(2, 782), 128, 0, stream>>>(
        x_paper, wt_lin[0], lin_b[0], xs, 100000, 128, 256, 1, (float*)nullptr, nullptr, 0);
    gemm_mfma<float><<<dim3(2, 391), 128, 0, stream>>>(
        x_author, wt_lin[1], lin_b[1], xs + 100000L * 128, 50000, 128, 128, 1,
        (float*)nullptr, nullptr, 0);
    gemm_mfma<float><<<dim3(2, 40), 128, 0, stream>>>(
        x_inst, wt_lin[2], lin_b[2], xs + 150000L * 128, 5000, 128, 64, 1,
        (float*)nullptr, nullptr, 0);

    // CSR build (shared by both layers)
    fill_u32<<<(NTOT + 255) / 256, 256, 0, stream>>>((unsigned int*)cursor, 0u, NTOT);
    for (int e = 0; e < 5; e++)
        count_edges<<<(ET_E[e] + 255) / 256, 256, 0, stream>>>(
            ei[e] + ET_E[e], ET_E[e], cursor + TB[ET_dst[e]]);
    scan_excl<<<1, 1024, 0, stream>>>(cursor, rowptr, NTOT);
    copy_u32<<<(NTOT + 255) / 256, 256, 0, stream>>>(rowptr, cursor, NTOT);
    static const int ET_ETL[5] = {0, 1, 0, 0, 1};
    for (int e = 0; e < 5; e++)
        scatter_edges<<<(ET_E[e] + 255) / 256, 256, 0, stream>>>(
            ei[e], ei[e] + ET_E[e], ET_E[e], cursor + TB[ET_dst[e]], recs,
            (int)NPRE[ET_src[e]], ET_ETL[e]);

    // layer 1 (output in-place over xs; gated skip fused into out-GEMM)
    float* outs1[3] = {xs, xs + 100000L * 128, xs + 150000L * 128};
    hgt_layer_run<float>(stream, ei, xs, kqvB, scB, rowptr, recs, aggB, krelB, vrelB,
                         wt_kqv1, kqv_b1, krel1, vrel1, prel1, wt_out1, out_b1, skip1,
                         8, 128, true, outs1);

    float* out = (float*)d_out;
    float* outs2[3] = {out, out + 100000L * 64, out + 150000L * 64};
    hgt_layer_run<float>(stream, ei, xs, kqvB, scB, rowptr, recs, aggB, krelB, vrelB,
                         wt_kqv2, kqv_b2, krel2, vrel2, prel2, wt_out2, out_b2, skip2,
                         4, 64, false, outs2);
}